// Round 4
// baseline (198.135 us; speedup 1.0000x reference)
//
#include <hip/hip_runtime.h>

// NAVAR dims (fixed by the problem)
#define T_LEN   2048
#define BATCH   8
#define HIDDEN  16
#define KSZ     4
#define NVAR    12
#define NGROUPS 96      // ND*NS*NV = 2*4*12
#define TILE_OUT 232    // outputs per block tile
#define BUF     256     // TILE_OUT + HALO
#define HALO    24      // 3*(1+1+2+4) receptive-field halo
#define NTILES  9       // ceil(2048/232)
#define PAD     16      // left pad rows so dilated taps (pos-12) stay in-bounds
#define NROWS   (BUF + PAD)   // 272 position rows
#define ROWCH   24      // 16 channels + 8 pad (48 B rows: 16-B aligned, ~2-way banks)

typedef __attribute__((ext_vector_type(8))) short bf16x8;   // MFMA A/B frag
typedef __attribute__((ext_vector_type(4))) float f32x4;    // MFMA C/D frag

// fp32 pair -> packed bf16x2 via HW RNE convert (no builtin on gfx950; T12
// recipe). Same rounding as the old integer emulation, 1 inst vs ~10.
__device__ __forceinline__ unsigned cvtpk(float lo, float hi) {
    unsigned r;
    asm("v_cvt_pk_bf16_f32 %0, %1, %2" : "=v"(r) : "v"(lo), "v"(hi));
    return r;
}

// ---------------------------------------------------------------------------
// One hidden layer (16->16, kernel 4, dilation D) as 2 MFMAs per 16-pos tile.
// Logical k' = kk*16 + i (tap-major). Lane (q=lane>>4, c=lane&15) supplies:
//   A[m=c][k=q*8+j]           (converted in-register at block start)
//   B[k=q*8+j][n=c]           (LDS  b128: 8 channels, tap row per (q,half))
// and receives D rows o=q*4+r at col pos=c -> ds_write_b64 (4 channels).
// Validity: output valid at pos>=6D reads prev positions >=3D (= prev minP).
// Garbage below that is finite-or-NaN but never feeds a valid output.
// ---------------------------------------------------------------------------
template<int D>
__device__ __forceinline__ void mfma_layer(
        const unsigned short (*__restrict__ src)[ROWCH],
        unsigned short (*__restrict__ dst)[ROWCH],
        const bf16x8 a0, const bf16x8 a1, const f32x4 bias,
        int tile, int wv, int q, int c) {
    const int ch = (q & 1) * 8;            // channel half this q supplies
    const int d0 = (3 - (q >> 1)) * D;     // tap offset, MFMA#0 (kk = q>>1)
    const int d1 = (1 - (q >> 1)) * D;     // tap offset, MFMA#1 (kk = 2+(q>>1))

    #pragma unroll
    for (int tt = 0; tt < 4; ++tt) {
        const int pos = (wv * 4 + tt) * 16 + c;
        const bf16x8 b0 = *(const bf16x8*)&src[PAD + pos - d0][ch];
        const bf16x8 b1 = *(const bf16x8*)&src[PAD + pos - d1][ch];
        f32x4 acc = bias;
        acc = __builtin_amdgcn_mfma_f32_16x16x32_bf16(a0, b0, acc, 0, 0, 0);
        acc = __builtin_amdgcn_mfma_f32_16x16x32_bf16(a1, b1, acc, 0, 0, 0);
        const int tgp = tile * TILE_OUT + pos - HALO;   // causal zero-pad
        uint2 pku;
        pku.x = cvtpk(fmaxf(acc[0], 0.f), fmaxf(acc[1], 0.f));
        pku.y = cvtpk(fmaxf(acc[2], 0.f), fmaxf(acc[3], 0.f));
        if (tgp < 0) { pku.x = 0u; pku.y = 0u; }
        *(uint2*)&dst[PAD + pos][q * 4] = pku;          // ds_write_b64
    }
}

// ---------------------------------------------------------------------------
// One block per (batch, group, time-tile). Weight pack fused into prologue
// (fp32 -> bf16 frags in-register; bit-identical to the old navar_pack path).
// Input conv via __shfl_up taps (no xs stage / no first barrier), 3 MFMA
// hidden layers (ping-pong transposed bf16 LDS), output 1x1 conv as ONE MFMA
// (K=32 with zero-padded A) storing straight to global.
// LDS = 2*272*24*2 = 26112 B -> 6 blocks/CU.
// ---------------------------------------------------------------------------
__global__ __launch_bounds__(256, 6) void navar_main(
        const float* __restrict__ x,
        const float* __restrict__ w_in,  const float* __restrict__ b_in,
        const float* __restrict__ w_h,   const float* __restrict__ b_h,
        const float* __restrict__ w_out, const float* __restrict__ b_out,
        float* __restrict__ contrib) {
    __shared__ unsigned short hb[2][NROWS][ROWCH];   // transposed: [pos][ch]

    const int p    = threadIdx.x;
    const int tile = blockIdx.x % NTILES;
    const int sg   = blockIdx.x / NTILES;
    const int b    = sg / NGROUPS;
    const int g    = sg % NGROUPS;
    const int tg   = tile * TILE_OUT + p - HALO;

    const int wv = p >> 6, q = (p >> 4) & 3, c = p & 15;
    const int kk = q >> 1;                 // tap-pair selector

    // ---- fused pack: load fp32 weights, convert to bf16 frags in-register.
    // A0[l][j] = bf(w_h[row*64 + i*4 + kk]),   i=(q&1)*8+j, kk=q>>1
    // A1[l][j] = bf(w_h[row*64 + i*4 + kk+2])  -> elems [kk] / [kk+2] of the
    // aligned float4 at row*64 + (q&1)*32 + 4j.
    bf16x8 A0[3], A1[3]; f32x4 BH[3];
    #pragma unroll
    for (int l = 0; l < 3; ++l) {
        const float* wrow = w_h
            + ((size_t)((l * NGROUPS + g) * HIDDEN + c) << 6) + (q & 1) * 32;
        float a0f[8], a1f[8];
        #pragma unroll
        for (int j = 0; j < 8; ++j) {
            const float4 v4 = *(const float4*)(wrow + 4 * j);
            a0f[j] = kk ? v4.y : v4.x;     // elem[kk]
            a1f[j] = kk ? v4.w : v4.z;     // elem[kk+2]
        }
        union { uint4 u; bf16x8 h; } r0, r1;
        r0.u = make_uint4(cvtpk(a0f[0], a0f[1]), cvtpk(a0f[2], a0f[3]),
                          cvtpk(a0f[4], a0f[5]), cvtpk(a0f[6], a0f[7]));
        r1.u = make_uint4(cvtpk(a1f[0], a1f[1]), cvtpk(a1f[2], a1f[3]),
                          cvtpk(a1f[4], a1f[5]), cvtpk(a1f[6], a1f[7]));
        A0[l] = r0.h; A1[l] = r1.h;
        BH[l] = *(const f32x4*)(b_h + (l * NGROUPS + g) * HIDDEN + q * 4);
    }
    // Output 1x1 weights: A row m=c (zero for c>=12), k=q*8+j (zero for q>=2).
    union { uint4 u; bf16x8 h; } ro;
    ro.u = make_uint4(0u, 0u, 0u, 0u);
    if (q < 2 && c < NVAR) {
        const float* wo = w_out + (size_t)(g * NVAR + c) * HIDDEN + q * 8;
        const float4 v0 = *(const float4*)(wo);
        const float4 v1 = *(const float4*)(wo + 4);
        ro.u = make_uint4(cvtpk(v0.x, v0.y), cvtpk(v0.z, v0.w),
                          cvtpk(v1.x, v1.y), cvtpk(v1.z, v1.w));
    }
    const bf16x8 AO = ro.h;
    f32x4 BO = {0.f, 0.f, 0.f, 0.f};
    if (q < 3) BO = *(const f32x4*)(b_out + g * NVAR + q * 4);

    // ---- x load + input conv 1->16 fp32 (taps via wave shuffle) ----
    const size_t xrow = (size_t)(b * NGROUPS + g) * T_LEN;
    const float xv = (tg >= 0 && tg < T_LEN) ? x[xrow + tg] : 0.f;
    float t2 = __shfl_up(xv, 1);           // all lanes active here
    float t1 = __shfl_up(xv, 2);
    float t0 = __shfl_up(xv, 3);
    if (p >= 3) {
        if ((p & 63) < 3) {                // wave-boundary lanes: refetch
            t0 = (tg >= 3 && tg - 3 < T_LEN) ? x[xrow + tg - 3] : 0.f;
            t1 = (tg >= 2 && tg - 2 < T_LEN) ? x[xrow + tg - 2] : 0.f;
            t2 = (tg >= 1 && tg - 1 < T_LEN) ? x[xrow + tg - 1] : 0.f;
        }
        const float t3 = xv;
        const float* w  = w_in + g * HIDDEN * KSZ;   // block-uniform -> s_load
        const float* bb = b_in + g * HIDDEN;
        unsigned pk[8];
        #pragma unroll
        for (int o = 0; o < HIDDEN; o += 2) {
            float e0 = fmaf(w[o*4+0], t0, bb[o]);
            e0 = fmaf(w[o*4+1], t1, e0);
            e0 = fmaf(w[o*4+2], t2, e0);
            e0 = fmaf(w[o*4+3], t3, e0);
            float e1 = fmaf(w[o*4+4], t0, bb[o+1]);
            e1 = fmaf(w[o*4+5], t1, e1);
            e1 = fmaf(w[o*4+6], t2, e1);
            e1 = fmaf(w[o*4+7], t3, e1);
            const unsigned u = cvtpk(fmaxf(e0, 0.f), fmaxf(e1, 0.f));
            pk[o >> 1] = (tg >= 0) ? u : 0u;
        }
        uint4* row = (uint4*)&hb[0][PAD + p][0];
        row[0] = make_uint4(pk[0], pk[1], pk[2], pk[3]);
        row[1] = make_uint4(pk[4], pk[5], pk[6], pk[7]);
    }
    __syncthreads();

    // ---- 3 dilated hidden blocks via MFMA (ping-pong) ----
    mfma_layer<1>(hb[0], hb[1], A0[0], A1[0], BH[0], tile, wv, q, c);
    __syncthreads();
    mfma_layer<2>(hb[1], hb[0], A0[1], A1[1], BH[1], tile, wv, q, c);
    __syncthreads();
    mfma_layer<4>(hb[0], hb[1], A0[2], A1[2], BH[2], tile, wv, q, c);
    __syncthreads();

    // ---- output 1x1 conv 16->12 as one MFMA; D rows=v, cols=pos ----
    {
        const int gds = g / NVAR, srcv = g % NVAR;
        #pragma unroll
        for (int tt = 0; tt < 4; ++tt) {
            const int pos = (wv * 4 + tt) * 16 + c;
            const bf16x8 b0 = *(const bf16x8*)&hb[1][PAD + pos][(q & 1) * 8];
            f32x4 acc = BO;
            acc = __builtin_amdgcn_mfma_f32_16x16x32_bf16(AO, b0, acc, 0, 0, 0);
            const int tgp = tile * TILE_OUT + pos - HALO;
            if (q < 3 && pos >= HALO && tgp < T_LEN) {
                const size_t base =
                    (((size_t)b * NGROUPS + gds * NVAR) * NVAR + srcv) * T_LEN + tgp;
                #pragma unroll
                for (int r = 0; r < 4; ++r)   // v = q*4+r; lanes c -> coalesced tg
                    contrib[base + (size_t)(q * 4 + r) * NVAR * T_LEN] = acc[r];
            }
        }
    }
}

// ---------------------------------------------------------------------------
// prediction[b,ds,v,t] = biases[ds,v] + sum_src contrib[b,ds,v,src,t]
// ---------------------------------------------------------------------------
__global__ __launch_bounds__(256) void navar_pred(
        const float* __restrict__ contrib, const float* __restrict__ biases,
        float* __restrict__ pred) {
    const int e = (blockIdx.x * 256 + threadIdx.x) * 4;
    const int t = e % T_LEN;
    const int G = e / T_LEN;
    const float4* c = (const float4*)(contrib + (size_t)G * NVAR * T_LEN + t);
    const float bias = biases[G % NGROUPS];
    float4 acc = make_float4(bias, bias, bias, bias);
    #pragma unroll
    for (int s = 0; s < NVAR; ++s) {
        float4 v = c[(size_t)s * (T_LEN / 4)];
        acc.x += v.x; acc.y += v.y; acc.z += v.z; acc.w += v.w;
    }
    *(float4*)(pred + e) = acc;
}

extern "C" void kernel_launch(void* const* d_in, const int* in_sizes, int n_in,
                              void* d_out, int out_size, void* d_ws, size_t ws_size,
                              hipStream_t stream) {
    const float* x      = (const float*)d_in[0];
    const float* w_in   = (const float*)d_in[1];
    const float* b_in   = (const float*)d_in[2];
    const float* w_h    = (const float*)d_in[3];
    const float* b_h    = (const float*)d_in[4];
    const float* w_out  = (const float*)d_in[5];
    const float* b_out  = (const float*)d_in[6];
    const float* biases = (const float*)d_in[7];

    float* pred    = (float*)d_out;                               // 8*96*2048 floats
    float* contrib = pred + (size_t)BATCH * NGROUPS * T_LEN;      // 8*96*12*2048 floats
    (void)d_ws; (void)ws_size;                                    // pack fused into main

    // main: one block per (batch, group, tile); packs its own weights
    navar_main<<<BATCH * NGROUPS * NTILES, 256, 0, stream>>>(
        x, w_in, b_in, w_h, b_h, w_out, b_out, contrib);
    // prediction reduction: BATCH*NGROUPS*T_LEN / (256*4) = 1536 blocks
    navar_pred<<<(BATCH * NGROUPS * T_LEN) / (256 * 4), 256, 0, stream>>>(
        contrib, biases, pred);
}

// Round 5
// 144.957 us; speedup vs baseline: 1.3669x; 1.3669x over previous
//
#include <hip/hip_runtime.h>

// NAVAR dims (fixed by the problem)
#define T_LEN   2048
#define BATCH   8
#define HIDDEN  16
#define KSZ     4
#define NVAR    12
#define NGROUPS 96      // ND*NS*NV = 2*4*12
#define TILE_OUT 232    // outputs per block tile
#define BUF     256     // TILE_OUT + HALO
#define HALO    24      // 3*(1+1+2+4) receptive-field halo
#define NTILES  9       // ceil(2048/232)
#define PAD     16      // left pad rows so dilated taps (pos-12) stay in-bounds
#define NROWS   (BUF + PAD)   // 272 position rows
#define ROWCH   24      // 16 channels + 8 pad (48 B rows: 16-B aligned, ~2-way banks)

#define NWH  (3 * NGROUPS * HIDDEN * HIDDEN * KSZ)   // 294912 hidden weights
#define NWO  (NGROUPS * HIDDEN * 32)                 // 49152 padded out weights

typedef __attribute__((ext_vector_type(8))) short bf16x8;   // MFMA A/B frag
typedef __attribute__((ext_vector_type(4))) float f32x4;    // MFMA C/D frag

__device__ __forceinline__ unsigned short f2bf(float x) {   // fp32 -> bf16 RNE
    union { float f; unsigned u; } v; v.f = x;
    unsigned r = v.u + 0x7FFFu + ((v.u >> 16) & 1u);
    return (unsigned short)(r >> 16);
}

// fp32 pair -> packed bf16x2 via HW RNE convert (no builtin on gfx950; T12
// recipe). Same RNE rounding as f2bf (verified R4: absmax unchanged).
__device__ __forceinline__ unsigned cvtpk(float lo, float hi) {
    unsigned r;
    asm("v_cvt_pk_bf16_f32 %0, %1, %2" : "=v"(r) : "v"(lo), "v"(hi));
    return r;
}

// ---------------------------------------------------------------------------
// Pack weights to bf16 with MFMA-friendly k-order (runs once, ~3 us).
// Hidden: wp[row][k'] with k' = kk*16 + i  (tap-major!), row = (l*96+g)*16+o.
//   -> A-frag = contiguous 8 k' ; B-frag = 8 consecutive CHANNELS at ONE tap
//      position => single ds_read_b128 from the transposed activation buffer.
// Out:   wpo[(g*16+m)*32 + k] = w_out[g][m][k] for m<12,k<16 else 0.
// ---------------------------------------------------------------------------
__global__ __launch_bounds__(256) void navar_pack(
        const float* __restrict__ w_h, const float* __restrict__ w_out,
        unsigned short* __restrict__ wp, unsigned short* __restrict__ wpo) {
    const int e = blockIdx.x * 256 + threadIdx.x;   // grid covers NWH+NWO exactly
    if (e < NWH) {
        const int k  = e & 63, row = e >> 6;
        const int kk = k >> 4, i = k & 15;
        wp[e] = f2bf(w_h[(row << 6) + i * 4 + kk]);
    } else {
        const int e2 = e - NWH;
        const int k = e2 & 31, m = (e2 >> 5) & 15, g = e2 >> 9;
        wpo[e2] = (k < 16 && m < 12) ? f2bf(w_out[(g * NVAR + m) * HIDDEN + k])
                                     : (unsigned short)0;
    }
}

// ---------------------------------------------------------------------------
// One hidden layer (16->16, kernel 4, dilation D) as 2 MFMAs per 16-pos tile.
// Logical k' = kk*16 + i. Lane (q=lane>>4, c=lane&15) supplies:
//   A[m=c][k=q*8+j]           (prefetched in registers at block start)
//   B[k=q*8+j][n=c]           (LDS  b128: 8 channels, tap row per (q,half))
// and receives D rows o=q*4+r at col pos=c -> ds_write_b64 (4 channels).
// Validity: output valid at pos>=6D reads prev positions >=3D (= prev minP).
// Garbage below that is finite-or-NaN but never feeds a valid output.
// ---------------------------------------------------------------------------
template<int D>
__device__ __forceinline__ void mfma_layer(
        const unsigned short (*__restrict__ src)[ROWCH],
        unsigned short (*__restrict__ dst)[ROWCH],
        const bf16x8 a0, const bf16x8 a1, const f32x4 bias,
        int tile, int wv, int q, int c) {
    const int ch = (q & 1) * 8;            // channel half this q supplies
    const int d0 = (3 - (q >> 1)) * D;     // tap offset, MFMA#0 (kk = q>>1)
    const int d1 = (1 - (q >> 1)) * D;     // tap offset, MFMA#1 (kk = 2+(q>>1))

    #pragma unroll
    for (int tt = 0; tt < 4; ++tt) {
        const int pos = (wv * 4 + tt) * 16 + c;
        const bf16x8 b0 = *(const bf16x8*)&src[PAD + pos - d0][ch];
        const bf16x8 b1 = *(const bf16x8*)&src[PAD + pos - d1][ch];
        f32x4 acc = bias;
        acc = __builtin_amdgcn_mfma_f32_16x16x32_bf16(a0, b0, acc, 0, 0, 0);
        acc = __builtin_amdgcn_mfma_f32_16x16x32_bf16(a1, b1, acc, 0, 0, 0);
        const int tgp = tile * TILE_OUT + pos - HALO;   // causal zero-pad
        uint2 pku;
        pku.x = cvtpk(fmaxf(acc[0], 0.f), fmaxf(acc[1], 0.f));
        pku.y = cvtpk(fmaxf(acc[2], 0.f), fmaxf(acc[3], 0.f));
        if (tgp < 0) { pku.x = 0u; pku.y = 0u; }
        *(uint2*)&dst[PAD + pos][q * 4] = pku;          // ds_write_b64
    }
}

// ---------------------------------------------------------------------------
// One block per (batch, group, time-tile). Input conv fp32 (K=4, cheap),
// 3 MFMA hidden layers (ping-pong transposed bf16 LDS), output 1x1 conv as
// ONE MFMA (K=32 with zero-padded A) storing straight to global.
// All MFMA A-frags + biases prefetched to registers BEFORE the first barrier
// (coalesced 64B-per-row reads of the PACKED bf16 weights — NOT the fp32
// originals; R4 showed per-block fp32 gather costs ~50 us in L2 transactions).
// LDS = 2*272*24*2 = 26112 B -> 6 blocks/CU.
// ---------------------------------------------------------------------------
__global__ __launch_bounds__(256, 6) void navar_main(
        const float* __restrict__ x,
        const float* __restrict__ w_in,  const float* __restrict__ b_in,
        const unsigned short* __restrict__ wp, const float* __restrict__ b_h,
        const unsigned short* __restrict__ wpo, const float* __restrict__ b_out,
        float* __restrict__ contrib) {
    __shared__ unsigned short hb[2][NROWS][ROWCH];   // transposed: [pos][ch]
    float* xs = (float*)&hb[1][0][0];                // alias: hb[1] dead until L1

    const int p    = threadIdx.x;
    const int tile = blockIdx.x % NTILES;
    const int sg   = blockIdx.x / NTILES;
    const int b    = sg / NGROUPS;
    const int g    = sg % NGROUPS;
    const int tg   = tile * TILE_OUT + p - HALO;

    const int wv = p >> 6, q = (p >> 4) & 3, c = p & 15;

    // ---- prefetch ALL MFMA operands into registers (statically indexed) ----
    const size_t wstep = (size_t)NGROUPS * HIDDEN * (HIDDEN * KSZ);   // per-layer
    const unsigned short* wr0 =
        wp + (size_t)(g * HIDDEN + c) * (HIDDEN * KSZ);
    bf16x8 A0[3], A1[3]; f32x4 BH[3];
    #pragma unroll
    for (int l = 0; l < 3; ++l) {
        A0[l] = *(const bf16x8*)(wr0 + l * wstep + q * 8);        // k' = q*8+j
        A1[l] = *(const bf16x8*)(wr0 + l * wstep + 32 + q * 8);   // k' = 32+q*8+j
        BH[l] = *(const f32x4*)(b_h + (l * NGROUPS + g) * HIDDEN + q * 4);
    }
    const unsigned short* wrowo = wpo + (size_t)(g * HIDDEN + c) * 32;
    const bf16x8 AO = *(const bf16x8*)(wrowo + q * 8);            // zeros q>=2
    f32x4 BO = {0.f, 0.f, 0.f, 0.f};
    if (q < 3) BO = *(const f32x4*)(b_out + g * NVAR + q * 4);

    // ---- stage x window ----
    float xv = 0.f;
    if (tg >= 0 && tg < T_LEN) xv = x[(size_t)(b * NGROUPS + g) * T_LEN + tg];
    xs[p] = xv;
    __syncthreads();

    // ---- input conv 1->16 fp32; pack 16 bf16 -> 32 B ds_write_b128 x2 ----
    if (p >= 3) {
        const float t0 = xs[p-3], t1 = xs[p-2], t2 = xs[p-1], t3 = xs[p];
        const float* w  = w_in + g * HIDDEN * KSZ;   // block-uniform -> s_load
        const float* bb = b_in + g * HIDDEN;
        unsigned pk[8];
        #pragma unroll
        for (int o = 0; o < HIDDEN; o += 2) {
            float e0 = fmaf(w[o*4+0], t0, bb[o]);
            e0 = fmaf(w[o*4+1], t1, e0);
            e0 = fmaf(w[o*4+2], t2, e0);
            e0 = fmaf(w[o*4+3], t3, e0);
            float e1 = fmaf(w[o*4+4], t0, bb[o+1]);
            e1 = fmaf(w[o*4+5], t1, e1);
            e1 = fmaf(w[o*4+6], t2, e1);
            e1 = fmaf(w[o*4+7], t3, e1);
            const unsigned u = cvtpk(fmaxf(e0, 0.f), fmaxf(e1, 0.f));
            pk[o >> 1] = (tg >= 0) ? u : 0u;
        }
        uint4* row = (uint4*)&hb[0][PAD + p][0];
        row[0] = make_uint4(pk[0], pk[1], pk[2], pk[3]);
        row[1] = make_uint4(pk[4], pk[5], pk[6], pk[7]);
    }
    __syncthreads();

    // ---- 3 dilated hidden blocks via MFMA (ping-pong) ----
    mfma_layer<1>(hb[0], hb[1], A0[0], A1[0], BH[0], tile, wv, q, c); // clobbers xs: ok
    __syncthreads();
    mfma_layer<2>(hb[1], hb[0], A0[1], A1[1], BH[1], tile, wv, q, c);
    __syncthreads();
    mfma_layer<4>(hb[0], hb[1], A0[2], A1[2], BH[2], tile, wv, q, c);
    __syncthreads();

    // ---- output 1x1 conv 16->12 as one MFMA; D rows=v, cols=pos ----
    {
        const int gds = g / NVAR, srcv = g % NVAR;
        #pragma unroll
        for (int tt = 0; tt < 4; ++tt) {
            const int pos = (wv * 4 + tt) * 16 + c;
            const bf16x8 b0 = *(const bf16x8*)&hb[1][PAD + pos][(q & 1) * 8];
            f32x4 acc = BO;
            acc = __builtin_amdgcn_mfma_f32_16x16x32_bf16(AO, b0, acc, 0, 0, 0);
            const int tgp = tile * TILE_OUT + pos - HALO;
            if (q < 3 && pos >= HALO && tgp < T_LEN) {
                const size_t base =
                    (((size_t)b * NGROUPS + gds * NVAR) * NVAR + srcv) * T_LEN + tgp;
                #pragma unroll
                for (int r = 0; r < 4; ++r)   // v = q*4+r; lanes c -> coalesced tg
                    contrib[base + (size_t)(q * 4 + r) * NVAR * T_LEN] = acc[r];
            }
        }
    }
}

// ---------------------------------------------------------------------------
// prediction[b,ds,v,t] = biases[ds,v] + sum_src contrib[b,ds,v,src,t]
// ---------------------------------------------------------------------------
__global__ __launch_bounds__(256) void navar_pred(
        const float* __restrict__ contrib, const float* __restrict__ biases,
        float* __restrict__ pred) {
    const int e = (blockIdx.x * 256 + threadIdx.x) * 4;
    const int t = e % T_LEN;
    const int G = e / T_LEN;
    const float4* c = (const float4*)(contrib + (size_t)G * NVAR * T_LEN + t);
    const float bias = biases[G % NGROUPS];
    float4 acc = make_float4(bias, bias, bias, bias);
    #pragma unroll
    for (int s = 0; s < NVAR; ++s) {
        float4 v = c[(size_t)s * (T_LEN / 4)];
        acc.x += v.x; acc.y += v.y; acc.z += v.z; acc.w += v.w;
    }
    *(float4*)(pred + e) = acc;
}

extern "C" void kernel_launch(void* const* d_in, const int* in_sizes, int n_in,
                              void* d_out, int out_size, void* d_ws, size_t ws_size,
                              hipStream_t stream) {
    const float* x      = (const float*)d_in[0];
    const float* w_in   = (const float*)d_in[1];
    const float* b_in   = (const float*)d_in[2];
    const float* w_h    = (const float*)d_in[3];
    const float* b_h    = (const float*)d_in[4];
    const float* w_out  = (const float*)d_in[5];
    const float* b_out  = (const float*)d_in[6];
    const float* biases = (const float*)d_in[7];

    float* pred    = (float*)d_out;                               // 8*96*2048 floats
    float* contrib = pred + (size_t)BATCH * NGROUPS * T_LEN;      // 8*96*12*2048 floats
    unsigned short* wp  = (unsigned short*)d_ws;                  // NWH bf16
    unsigned short* wpo = wp + NWH;                               // NWO bf16

    // pack hidden + output weights to bf16 (k-reordered)
    navar_pack<<<(NWH + NWO) / 256, 256, 0, stream>>>(w_h, w_out, wp, wpo);
    // main: one block per (batch, group, tile)
    navar_main<<<BATCH * NGROUPS * NTILES, 256, 0, stream>>>(
        x, w_in, b_in, wp, b_h, wpo, b_out, contrib);
    // prediction reduction: BATCH*NGROUPS*T_LEN / (256*4) = 1536 blocks
    navar_pred<<<(BATCH * NGROUPS * T_LEN) / (256 * 4), 256, 0, stream>>>(
        contrib, biases, pred);
}